// Round 8
// baseline (125.560 us; speedup 1.0000x reference)
//
#include <hip/hip_runtime.h>

#define SMOOTH 1e-5f

typedef float floatx4 __attribute__((ext_vector_type(4)));
typedef float floatx2 __attribute__((ext_vector_type(2)));

// ws[scale][img][5] = {C, S, inter, z_sum, p_sum}

__device__ __forceinline__ float wave_reduce(float v) {
#pragma unroll
    for (int off = 32; off; off >>= 1) v += __shfl_down(v, off, 64);
    return v;
}

__device__ __forceinline__ float sigmoidf(float x) {
    return 1.f / (1.f + __expf(-x));
}

__device__ __forceinline__ unsigned pack8(int4 a, int4 b) {
    return (unsigned)(a.x != 0)        | ((unsigned)(a.y != 0) << 1) |
           ((unsigned)(a.z != 0) << 2) | ((unsigned)(a.w != 0) << 3) |
           ((unsigned)(b.x != 0) << 4) | ((unsigned)(b.y != 0) << 5) |
           ((unsigned)(b.z != 0) << 6) | ((unsigned)(b.w != 0) << 7);
}
__device__ __forceinline__ unsigned pack4(int4 a, int4 b) {   // even elements
    return (unsigned)(a.x != 0)        | ((unsigned)(a.z != 0) << 1) |
           ((unsigned)(b.x != 0) << 2) | ((unsigned)(b.z != 0) << 3);
}
__device__ __forceinline__ unsigned pack2(int a, int b) {
    return (unsigned)(a != 0) | ((unsigned)(b != 0) << 1);
}

// Bit-stencil one row of W px/lane. u,c,d = packed fg bits; pr = probs.
template<int W>
__device__ __forceinline__ void row_proc(unsigned u, unsigned c, unsigned d,
    const float* pr, int lane, int& cC, int& cS, float& aI, float& aZ, float& aP)
{
    unsigned pv = __shfl_up(c, 1);
    unsigned nx = __shfl_down(c, 1);
    if (lane == 0)  pv = 0;
    if (lane == 63) nx = 0;
    const unsigned M = (1u << W) - 1u;
    unsigned lv = ((c << 1) | ((pv >> (W - 1)) & 1u)) & M;
    unsigned rv = ((c >> 1) | ((nx & 1u) << (W - 1))) & M;
    unsigned inter = c & u & d & lv & rv;
    cS += __popc(c);
    cC += __popc(c & ~inter);
#pragma unroll
    for (int j = 0; j < W; ++j) {
        float pj = pr[j];
        aI += ((c >> j) & 1u) ? pj : 0.f;
        aZ += pj * pj;
        aP += pj;
    }
}

// 1792 single-wave blocks (7/CU exactly). Wave = one full row width; each wave
// owns a 16-row strip and slides down 1 row/iter, prefetching next row's
// target+logits before computing the current row (software pipeline).
//   blk    0..1023: scale0, 32 strips/img, 8 px/lane/row
//   blk 1024..1535: scale1, 16 strips/img, 4 px/lane/row
//   blk 1536..1791: scale2,  8 strips/img, 2 px/lane/row
__global__ __launch_bounds__(64) void bdou_reduce(
    const float* __restrict__ l0, const float* __restrict__ l1,
    const float* __restrict__ l2, const int* __restrict__ tgt,
    float* __restrict__ ws)
{
    const int blk  = blockIdx.x;
    const int lane = threadIdx.x;

    int scale, img, strip;
    if (blk < 1024)      { scale = 0; img = blk >> 5; strip = blk & 31; }
    else if (blk < 1536) { int b = blk - 1024; scale = 1; img = b >> 4; strip = b & 15; }
    else                 { int b = blk - 1536; scale = 2; img = b >> 3; strip = b & 7; }

    const int* __restrict__ timg = tgt + (size_t)img * 262144;
    const int y0 = strip * 16;

    int   cC = 0, cS = 0;
    float aI = 0.f, aZ = 0.f, aP = 0.f;

    if (scale == 0) {
        const int*   T = timg + lane * 8;
        const float* L = l0 + (size_t)img * 262144 + lane * 8;
        unsigned b_prev, b_cur, b_next;
        floatx4 lgA, lgB;
        {
            int yp = (y0 > 0) ? y0 - 1 : 0;
            int4 a0 = *(const int4*)(T + (size_t)yp * 512);
            int4 a1 = *(const int4*)(T + (size_t)yp * 512 + 4);
            int4 c0 = *(const int4*)(T + (size_t)y0 * 512);
            int4 c1 = *(const int4*)(T + (size_t)y0 * 512 + 4);
            int4 d0 = *(const int4*)(T + (size_t)(y0 + 1) * 512);
            int4 d1 = *(const int4*)(T + (size_t)(y0 + 1) * 512 + 4);
            lgA = *(const floatx4*)(L + (size_t)y0 * 512);
            lgB = *(const floatx4*)(L + (size_t)y0 * 512 + 4);
            b_prev = pack8(a0, a1); b_cur = pack8(c0, c1); b_next = pack8(d0, d1);
        }
        for (int i = 0; i < 16; ++i) {
            int y   = y0 + i;
            int ypf = (y + 2 < 512) ? y + 2 : 511;
            int ylg = (y + 1 < 512) ? y + 1 : 511;
            int4 p0 = *(const int4*)(T + (size_t)ypf * 512);
            int4 p1 = *(const int4*)(T + (size_t)ypf * 512 + 4);
            floatx4 nA = *(const floatx4*)(L + (size_t)ylg * 512);
            floatx4 nB = *(const floatx4*)(L + (size_t)ylg * 512 + 4);
            unsigned u = (y > 0)   ? b_prev : 0u;
            unsigned d = (y < 511) ? b_next : 0u;
            float pr[8] = {sigmoidf(lgA.x), sigmoidf(lgA.y), sigmoidf(lgA.z), sigmoidf(lgA.w),
                           sigmoidf(lgB.x), sigmoidf(lgB.y), sigmoidf(lgB.z), sigmoidf(lgB.w)};
            row_proc<8>(u, b_cur, d, pr, lane, cC, cS, aI, aZ, aP);
            b_prev = b_cur; b_cur = b_next; b_next = pack8(p0, p1);
            lgA = nA; lgB = nB;
        }
    } else if (scale == 1) {
        const int*   T = timg + lane * 8;            // full-res col base
        const float* L = l1 + (size_t)img * 65536 + lane * 4;
        unsigned b_prev, b_cur, b_next;
        floatx4 lgA;
        {
            int yp = (y0 > 0) ? y0 - 1 : 0;
            int4 a0 = *(const int4*)(T + (size_t)(2 * yp) * 512);
            int4 a1 = *(const int4*)(T + (size_t)(2 * yp) * 512 + 4);
            int4 c0 = *(const int4*)(T + (size_t)(2 * y0) * 512);
            int4 c1 = *(const int4*)(T + (size_t)(2 * y0) * 512 + 4);
            int4 d0 = *(const int4*)(T + (size_t)(2 * (y0 + 1)) * 512);
            int4 d1 = *(const int4*)(T + (size_t)(2 * (y0 + 1)) * 512 + 4);
            lgA = *(const floatx4*)(L + (size_t)y0 * 256);
            b_prev = pack4(a0, a1); b_cur = pack4(c0, c1); b_next = pack4(d0, d1);
        }
        for (int i = 0; i < 16; ++i) {
            int y   = y0 + i;
            int ypf = (y + 2 < 256) ? y + 2 : 255;
            int ylg = (y + 1 < 256) ? y + 1 : 255;
            int4 p0 = *(const int4*)(T + (size_t)(2 * ypf) * 512);
            int4 p1 = *(const int4*)(T + (size_t)(2 * ypf) * 512 + 4);
            floatx4 nA = *(const floatx4*)(L + (size_t)ylg * 256);
            unsigned u = (y > 0)   ? b_prev : 0u;
            unsigned d = (y < 255) ? b_next : 0u;
            float pr[4] = {sigmoidf(lgA.x), sigmoidf(lgA.y), sigmoidf(lgA.z), sigmoidf(lgA.w)};
            row_proc<4>(u, b_cur, d, pr, lane, cC, cS, aI, aZ, aP);
            b_prev = b_cur; b_cur = b_next; b_next = pack4(p0, p1);
            lgA = nA;
        }
    } else {
        const int*   T = timg + lane * 8;            // full-res col base
        const float* L = l2 + (size_t)img * 16384 + lane * 2;
        unsigned b_prev, b_cur, b_next;
        floatx2 lgA;
        {
            int yp = (y0 > 0) ? y0 - 1 : 0;
            int a0 = T[(size_t)(4 * yp) * 512],       a1 = T[(size_t)(4 * yp) * 512 + 4];
            int c0 = T[(size_t)(4 * y0) * 512],       c1 = T[(size_t)(4 * y0) * 512 + 4];
            int d0 = T[(size_t)(4 * (y0 + 1)) * 512], d1 = T[(size_t)(4 * (y0 + 1)) * 512 + 4];
            lgA = *(const floatx2*)(L + (size_t)y0 * 128);
            b_prev = pack2(a0, a1); b_cur = pack2(c0, c1); b_next = pack2(d0, d1);
        }
        for (int i = 0; i < 16; ++i) {
            int y   = y0 + i;
            int ypf = (y + 2 < 128) ? y + 2 : 127;
            int ylg = (y + 1 < 128) ? y + 1 : 127;
            int p0 = T[(size_t)(4 * ypf) * 512];
            int p1 = T[(size_t)(4 * ypf) * 512 + 4];
            floatx2 nA = *(const floatx2*)(L + (size_t)ylg * 128);
            unsigned u = (y > 0)   ? b_prev : 0u;
            unsigned d = (y < 127) ? b_next : 0u;
            float pr[2] = {sigmoidf(lgA.x), sigmoidf(lgA.y)};
            row_proc<2>(u, b_cur, d, pr, lane, cC, cS, aI, aZ, aP);
            b_prev = b_cur; b_cur = b_next; b_next = pack2(p0, p1);
            lgA = nA;
        }
    }

    // ---- wave reduce 5 partials, atomic into ws (single-wave block) ----
    float vals[5] = {(float)cC, (float)cS, aI, aZ, aP};
#pragma unroll
    for (int k = 0; k < 5; ++k) vals[k] = wave_reduce(vals[k]);
    if (lane == 0) {
        float* w = ws + (scale * 32 + img) * 5;
        atomicAdd(&w[0], vals[0]);
        atomicAdd(&w[1], vals[1]);
        atomicAdd(&w[2], vals[2]);
        atomicAdd(&w[3], vals[3]);
        atomicAdd(&w[4], vals[4]);
    }
}

// 128 threads: tid<96 -> one (scale,img) pair each; wave+LDS reduce.
__global__ void bdou_final(const float* __restrict__ ws,
                           const float* __restrict__ valid_mask,
                           float* __restrict__ out)
{
    int tid = threadIdx.x;
    float contrib = 0.f, cpart = 0.f;
    if (tid < 96) {
        int s = tid >> 5, i = tid & 31;
        const float* w = ws + tid * 5;
        float C = w[0], S = w[1], I = w[2], Z = w[3], P = w[4];
        float valid = (valid_mask[i] >= 0.5f) ? 1.f : 0.f;
        float alpha = fminf(2.f * (1.f - (C + SMOOTH) / (S + SMOOTH)) - 1.f, 0.8f);
        float dou = (Z + S - 2.f * I + SMOOTH) /
                    (Z + S - (1.f + alpha) * I + SMOOTH);
        const float wts[3]  = {4.f / 7.f, 2.f / 7.f, 1.f / 7.f};
        const float pixc[3] = {262144.f, 65536.f, 16384.f};
        float per = (S > 0.f) ? dou : (P / pixc[s]);
        contrib = wts[s] * per * valid;
        if (tid < 32) cpart = valid;
    }
    contrib = wave_reduce(contrib);
    cpart   = wave_reduce(cpart);
    __shared__ float sm[2][2];
    int wv = tid >> 6, ln = tid & 63;
    if (ln == 0) { sm[wv][0] = contrib; sm[wv][1] = cpart; }
    __syncthreads();
    if (tid == 0) {
        float tot = sm[0][0] + sm[1][0];
        float cnt = sm[0][1] + sm[1][1];
        out[0] = (cnt > 0.f) ? tot / cnt : 0.f;
    }
}

extern "C" void kernel_launch(void* const* d_in, const int* in_sizes, int n_in,
                              void* d_out, int out_size, void* d_ws, size_t ws_size,
                              hipStream_t stream) {
    const float* l0 = (const float*)d_in[0];
    const float* l1 = (const float*)d_in[1];
    const float* l2 = (const float*)d_in[2];
    const int*   tg = (const int*)d_in[3];
    const float* vm = (const float*)d_in[4];
    float* ws = (float*)d_ws;

    (void)hipMemsetAsync(ws, 0, 3 * 32 * 5 * sizeof(float), stream);
    bdou_reduce<<<1792, 64, 0, stream>>>(l0, l1, l2, tg, ws);
    bdou_final<<<1, 128, 0, stream>>>(ws, vm, (float*)d_out);
}

// Round 9
// 114.110 us; speedup vs baseline: 1.1003x; 1.1003x over previous
//
#include <hip/hip_runtime.h>

#define SMOOTH 1e-5f
#define SCHED_FENCE() __builtin_amdgcn_sched_barrier(0)

typedef float floatx4 __attribute__((ext_vector_type(4)));
typedef float floatx2 __attribute__((ext_vector_type(2)));

// ws[scale][img][5] = {C, S, inter, z_sum, p_sum}

__device__ __forceinline__ float wave_reduce(float v) {
#pragma unroll
    for (int off = 32; off; off >>= 1) v += __shfl_down(v, off, 64);
    return v;
}

__device__ __forceinline__ float sigmoidf(float x) {
    return 1.f / (1.f + __expf(-x));
}

__device__ __forceinline__ unsigned pack8(int4 a, int4 b) {
    return (unsigned)(a.x != 0)        | ((unsigned)(a.y != 0) << 1) |
           ((unsigned)(a.z != 0) << 2) | ((unsigned)(a.w != 0) << 3) |
           ((unsigned)(b.x != 0) << 4) | ((unsigned)(b.y != 0) << 5) |
           ((unsigned)(b.z != 0) << 6) | ((unsigned)(b.w != 0) << 7);
}
__device__ __forceinline__ unsigned pack4(int4 a, int4 b) {   // even elements
    return (unsigned)(a.x != 0)        | ((unsigned)(a.z != 0) << 1) |
           ((unsigned)(b.x != 0) << 2) | ((unsigned)(b.z != 0) << 3);
}
__device__ __forceinline__ unsigned pack2(int a, int b) {
    return (unsigned)(a != 0) | ((unsigned)(b != 0) << 1);
}

// Bit-stencil one row of W px/lane. u,c,d = packed fg bits; pr = probs.
template<int W>
__device__ __forceinline__ void row_proc(unsigned u, unsigned c, unsigned d,
    const float* pr, int lane, int& cC, int& cS, float& aI, float& aZ, float& aP)
{
    unsigned pv = __shfl_up(c, 1);
    unsigned nx = __shfl_down(c, 1);
    if (lane == 0)  pv = 0;
    if (lane == 63) nx = 0;
    const unsigned M = (1u << W) - 1u;
    unsigned lv = ((c << 1) | ((pv >> (W - 1)) & 1u)) & M;
    unsigned rv = ((c >> 1) | ((nx & 1u) << (W - 1))) & M;
    unsigned inter = c & u & d & lv & rv;
    cS += __popc(c);
    cC += __popc(c & ~inter);
#pragma unroll
    for (int j = 0; j < W; ++j) {
        float pj = pr[j];
        aI += ((c >> j) & 1u) ? pj : 0.f;
        aZ += pj * pj;
        aP += pj;
    }
}

// 1792 blocks x 256 thr (R7 shape). Wave = full row width, 4-row strip.
// sched_barrier(0) between load batch and consumption forces ALL loads to be
// issued before the first use -> real 20-deep MLP per wave (R6's VGPR=32
// proved the compiler otherwise serializes into load->wait->consume phases).
// __launch_bounds__(256,4): VGPR cap 128, >=16 waves/CU.
__global__ __launch_bounds__(256, 4) void bdou_reduce(
    const float* __restrict__ l0, const float* __restrict__ l1,
    const float* __restrict__ l2, const int* __restrict__ tgt,
    float* __restrict__ ws)
{
    const int blk = blockIdx.x;
    const int tid = threadIdx.x;
    const int w   = tid >> 6, lane = tid & 63;

    int scale, img, rb;
    if (blk < 1024)      { scale = 0; img = blk >> 5; rb = blk & 31; }
    else if (blk < 1536) { int b = blk - 1024; scale = 1; img = b >> 4; rb = b & 15; }
    else                 { int b = blk - 1536; scale = 2; img = b >> 3; rb = b & 7; }

    const int* __restrict__ timg = tgt + (size_t)img * 262144;
    const int y0 = rb * 16 + w * 4;          // wave-uniform first row

    int   cC = 0, cS = 0;
    float aI = 0.f, aZ = 0.f, aP = 0.f;

    if (scale == 0) {
        const int cc = lane * 8;
        const int* T = timg + (size_t)y0 * 512 + cc;
        const float* L = l0 + (size_t)img * 262144 + (size_t)y0 * 512 + cc;
        const int ou = (y0 > 0) ? -512 : 0;
        const unsigned mu = (y0 > 0) ? 0xFFu : 0u;
        const int od = (y0 + 4 <= 511) ? 4 * 512 : 3 * 512;
        const unsigned m4 = (y0 + 4 <= 511) ? 0xFFu : 0u;
        // ---- issue all 20 loads ----
        int4 ru0 = *(const int4*)(T + ou),       ru1 = *(const int4*)(T + ou + 4);
        int4 r00 = *(const int4*)(T),            r01 = *(const int4*)(T + 4);
        int4 r10 = *(const int4*)(T + 512),      r11 = *(const int4*)(T + 512 + 4);
        int4 r20 = *(const int4*)(T + 1024),     r21 = *(const int4*)(T + 1024 + 4);
        int4 r30 = *(const int4*)(T + 1536),     r31 = *(const int4*)(T + 1536 + 4);
        int4 r40 = *(const int4*)(T + od),       r41 = *(const int4*)(T + od + 4);
        floatx4 la0 = *(const floatx4*)(L),              la1 = *(const floatx4*)(L + 4);
        floatx4 lb0 = *(const floatx4*)(L + 512),        lb1 = *(const floatx4*)(L + 512 + 4);
        floatx4 lc0 = *(const floatx4*)(L + 1024),       lc1 = *(const floatx4*)(L + 1024 + 4);
        floatx4 ld0 = *(const floatx4*)(L + 1536),       ld1 = *(const floatx4*)(L + 1536 + 4);
        SCHED_FENCE();
        // ---- consume ----
        unsigned bu = pack8(ru0, ru1) & mu;
        unsigned b0 = pack8(r00, r01);
        unsigned b1 = pack8(r10, r11);
        unsigned b2 = pack8(r20, r21);
        unsigned b3 = pack8(r30, r31);
        unsigned b4 = pack8(r40, r41) & m4;
        float pr[8];
        pr[0]=sigmoidf(la0.x); pr[1]=sigmoidf(la0.y); pr[2]=sigmoidf(la0.z); pr[3]=sigmoidf(la0.w);
        pr[4]=sigmoidf(la1.x); pr[5]=sigmoidf(la1.y); pr[6]=sigmoidf(la1.z); pr[7]=sigmoidf(la1.w);
        row_proc<8>(bu, b0, b1, pr, lane, cC, cS, aI, aZ, aP);
        pr[0]=sigmoidf(lb0.x); pr[1]=sigmoidf(lb0.y); pr[2]=sigmoidf(lb0.z); pr[3]=sigmoidf(lb0.w);
        pr[4]=sigmoidf(lb1.x); pr[5]=sigmoidf(lb1.y); pr[6]=sigmoidf(lb1.z); pr[7]=sigmoidf(lb1.w);
        row_proc<8>(b0, b1, b2, pr, lane, cC, cS, aI, aZ, aP);
        pr[0]=sigmoidf(lc0.x); pr[1]=sigmoidf(lc0.y); pr[2]=sigmoidf(lc0.z); pr[3]=sigmoidf(lc0.w);
        pr[4]=sigmoidf(lc1.x); pr[5]=sigmoidf(lc1.y); pr[6]=sigmoidf(lc1.z); pr[7]=sigmoidf(lc1.w);
        row_proc<8>(b1, b2, b3, pr, lane, cC, cS, aI, aZ, aP);
        pr[0]=sigmoidf(ld0.x); pr[1]=sigmoidf(ld0.y); pr[2]=sigmoidf(ld0.z); pr[3]=sigmoidf(ld0.w);
        pr[4]=sigmoidf(ld1.x); pr[5]=sigmoidf(ld1.y); pr[6]=sigmoidf(ld1.z); pr[7]=sigmoidf(ld1.w);
        row_proc<8>(b2, b3, b4, pr, lane, cC, cS, aI, aZ, aP);
    } else if (scale == 1) {
        const int fc = lane * 8;                     // full-res col
        const int* T = timg + (size_t)(2 * y0) * 512 + fc;
        const float* L = l1 + (size_t)img * 65536 + (size_t)y0 * 256 + lane * 4;
        const int ou = (y0 > 0) ? -1024 : 0;
        const unsigned mu = (y0 > 0) ? 0xFu : 0u;
        const int od = (y0 + 4 <= 255) ? 4096 : 3072;
        const unsigned m4 = (y0 + 4 <= 255) ? 0xFu : 0u;
        int4 ru0 = *(const int4*)(T + ou),   ru1 = *(const int4*)(T + ou + 4);
        int4 r00 = *(const int4*)(T),        r01 = *(const int4*)(T + 4);
        int4 r10 = *(const int4*)(T + 1024), r11 = *(const int4*)(T + 1024 + 4);
        int4 r20 = *(const int4*)(T + 2048), r21 = *(const int4*)(T + 2048 + 4);
        int4 r30 = *(const int4*)(T + 3072), r31 = *(const int4*)(T + 3072 + 4);
        int4 r40 = *(const int4*)(T + od),   r41 = *(const int4*)(T + od + 4);
        floatx4 la = *(const floatx4*)(L);
        floatx4 lb = *(const floatx4*)(L + 256);
        floatx4 lc = *(const floatx4*)(L + 512);
        floatx4 ld = *(const floatx4*)(L + 768);
        SCHED_FENCE();
        unsigned bu = pack4(ru0, ru1) & mu;
        unsigned b0 = pack4(r00, r01);
        unsigned b1 = pack4(r10, r11);
        unsigned b2 = pack4(r20, r21);
        unsigned b3 = pack4(r30, r31);
        unsigned b4 = pack4(r40, r41) & m4;
        float pr[4];
        pr[0]=sigmoidf(la.x); pr[1]=sigmoidf(la.y); pr[2]=sigmoidf(la.z); pr[3]=sigmoidf(la.w);
        row_proc<4>(bu, b0, b1, pr, lane, cC, cS, aI, aZ, aP);
        pr[0]=sigmoidf(lb.x); pr[1]=sigmoidf(lb.y); pr[2]=sigmoidf(lb.z); pr[3]=sigmoidf(lb.w);
        row_proc<4>(b0, b1, b2, pr, lane, cC, cS, aI, aZ, aP);
        pr[0]=sigmoidf(lc.x); pr[1]=sigmoidf(lc.y); pr[2]=sigmoidf(lc.z); pr[3]=sigmoidf(lc.w);
        row_proc<4>(b1, b2, b3, pr, lane, cC, cS, aI, aZ, aP);
        pr[0]=sigmoidf(ld.x); pr[1]=sigmoidf(ld.y); pr[2]=sigmoidf(ld.z); pr[3]=sigmoidf(ld.w);
        row_proc<4>(b2, b3, b4, pr, lane, cC, cS, aI, aZ, aP);
    } else {
        const int fc = lane * 8;                     // full-res col
        const int* T = timg + (size_t)(4 * y0) * 512 + fc;
        const float* L = l2 + (size_t)img * 16384 + (size_t)y0 * 128 + lane * 2;
        const int ou = (y0 > 0) ? -2048 : 0;
        const unsigned mu = (y0 > 0) ? 3u : 0u;
        const int od = (y0 + 4 <= 127) ? 8192 : 6144;
        const unsigned m4 = (y0 + 4 <= 127) ? 3u : 0u;
        int ru0 = T[ou],   ru1 = T[ou + 4];
        int r00 = T[0],    r01 = T[4];
        int r10 = T[2048], r11 = T[2048 + 4];
        int r20 = T[4096], r21 = T[4096 + 4];
        int r30 = T[6144], r31 = T[6144 + 4];
        int r40 = T[od],   r41 = T[od + 4];
        floatx2 la = *(const floatx2*)(L);
        floatx2 lb = *(const floatx2*)(L + 128);
        floatx2 lc = *(const floatx2*)(L + 256);
        floatx2 ld = *(const floatx2*)(L + 384);
        SCHED_FENCE();
        unsigned bu = pack2(ru0, ru1) & mu;
        unsigned b0 = pack2(r00, r01);
        unsigned b1 = pack2(r10, r11);
        unsigned b2 = pack2(r20, r21);
        unsigned b3 = pack2(r30, r31);
        unsigned b4 = pack2(r40, r41) & m4;
        float pr[2];
        pr[0]=sigmoidf(la.x); pr[1]=sigmoidf(la.y);
        row_proc<2>(bu, b0, b1, pr, lane, cC, cS, aI, aZ, aP);
        pr[0]=sigmoidf(lb.x); pr[1]=sigmoidf(lb.y);
        row_proc<2>(b0, b1, b2, pr, lane, cC, cS, aI, aZ, aP);
        pr[0]=sigmoidf(lc.x); pr[1]=sigmoidf(lc.y);
        row_proc<2>(b1, b2, b3, pr, lane, cC, cS, aI, aZ, aP);
        pr[0]=sigmoidf(ld.x); pr[1]=sigmoidf(ld.y);
        row_proc<2>(b2, b3, b4, pr, lane, cC, cS, aI, aZ, aP);
    }

    // ---- block reduce 5 partials, atomic into ws ----
    float vals[5] = {(float)cC, (float)cS, aI, aZ, aP};
    __shared__ float red[4][5];
#pragma unroll
    for (int k = 0; k < 5; ++k) vals[k] = wave_reduce(vals[k]);
    if (lane == 0) {
#pragma unroll
        for (int k = 0; k < 5; ++k) red[w][k] = vals[k];
    }
    __syncthreads();
    if (tid < 5) {
        float s = red[0][tid] + red[1][tid] + red[2][tid] + red[3][tid];
        atomicAdd(&ws[(scale * 32 + img) * 5 + tid], s);
    }
}

// 128 threads: tid<96 -> one (scale,img) pair each; wave+LDS reduce.
__global__ void bdou_final(const float* __restrict__ ws,
                           const float* __restrict__ valid_mask,
                           float* __restrict__ out)
{
    int tid = threadIdx.x;
    float contrib = 0.f, cpart = 0.f;
    if (tid < 96) {
        int s = tid >> 5, i = tid & 31;
        const float* w = ws + tid * 5;
        float C = w[0], S = w[1], I = w[2], Z = w[3], P = w[4];
        float valid = (valid_mask[i] >= 0.5f) ? 1.f : 0.f;
        float alpha = fminf(2.f * (1.f - (C + SMOOTH) / (S + SMOOTH)) - 1.f, 0.8f);
        float dou = (Z + S - 2.f * I + SMOOTH) /
                    (Z + S - (1.f + alpha) * I + SMOOTH);
        const float wts[3]  = {4.f / 7.f, 2.f / 7.f, 1.f / 7.f};
        const float pixc[3] = {262144.f, 65536.f, 16384.f};
        float per = (S > 0.f) ? dou : (P / pixc[s]);
        contrib = wts[s] * per * valid;
        if (tid < 32) cpart = valid;
    }
    contrib = wave_reduce(contrib);
    cpart   = wave_reduce(cpart);
    __shared__ float sm[2][2];
    int wv = tid >> 6, ln = tid & 63;
    if (ln == 0) { sm[wv][0] = contrib; sm[wv][1] = cpart; }
    __syncthreads();
    if (tid == 0) {
        float tot = sm[0][0] + sm[1][0];
        float cnt = sm[0][1] + sm[1][1];
        out[0] = (cnt > 0.f) ? tot / cnt : 0.f;
    }
}

extern "C" void kernel_launch(void* const* d_in, const int* in_sizes, int n_in,
                              void* d_out, int out_size, void* d_ws, size_t ws_size,
                              hipStream_t stream) {
    const float* l0 = (const float*)d_in[0];
    const float* l1 = (const float*)d_in[1];
    const float* l2 = (const float*)d_in[2];
    const int*   tg = (const int*)d_in[3];
    const float* vm = (const float*)d_in[4];
    float* ws = (float*)d_ws;

    (void)hipMemsetAsync(ws, 0, 3 * 32 * 5 * sizeof(float), stream);
    bdou_reduce<<<1792, 256, 0, stream>>>(l0, l1, l2, tg, ws);
    bdou_final<<<1, 128, 0, stream>>>(ws, vm, (float*)d_out);
}